// Round 2
// baseline (790.085 us; speedup 1.0000x reference)
//
#include <hip/hip_runtime.h>
#include <stdint.h>

// PositionLinearAttention on MI355X. B=8, C=256, Cqk=32, N=16384.
// R6 == R5 occupancy restructure, resubmitted after infra failure, with the
// partial-S scratch kept in ws when it fits (d_out aliasing only as fallback).
//  - pass1: TN=128, one tile/block, grid 1024 (4 blk/CU, 16 waves/CU vs 8).
//    Phase A: thread=(pixel-pair, m-group of 16): float2 x loads, 4 w-float4
//    per channel per 32 FMA (vs 17 VMEM/64 FMA before), 32 accumulators.
//  - pass2: 2 pixels/thread, float2 loads/stores, matT rows amortized 2x.
//
// Reformulation (V never materialized):
//   S[b][m][c']   = sum_n Kn[b][m][n] * x[b][c'][n]
//   matrix[b][m][c] = sum_c' Wv[c][c'] S[b][m][c'] + bv[c]*ksraw[b][m]
//   value_sum[b][c] = sum_c' Wv[c][c'] x_sum[b][c'] + N*bv[c]
//   tailor[n] = 1/(N + Qn[n]·(ksraw+EPS))
//   out[b][c][n] = x + gamma*tailor[n]*(value_sum[c] + Qn[n]·matrix[:,c])

#define NB 8
#define NC 256
#define CQK 32
#define NPIX 16384
#define TN 128                       // pixels per pass1 tile
#define PB 128                       // pass1 blocks per batch = NPIX/TN
#define PARTF (CQK*NC + NC + CQK)    // 8480 floats per partial block
#define EPSV 1e-6f

typedef unsigned short bfraw;

__device__ __forceinline__ float bf2f(bfraw u) {
    union { uint32_t i; float f; } v; v.i = ((uint32_t)u) << 16; return v.f;
}
__device__ __forceinline__ void unpack8(uint4 raw, float* xv) {
    xv[0] = bf2f((bfraw)(raw.x & 0xffffu)); xv[1] = bf2f((bfraw)(raw.x >> 16));
    xv[2] = bf2f((bfraw)(raw.y & 0xffffu)); xv[3] = bf2f((bfraw)(raw.y >> 16));
    xv[4] = bf2f((bfraw)(raw.z & 0xffffu)); xv[5] = bf2f((bfraw)(raw.z >> 16));
    xv[6] = bf2f((bfraw)(raw.w & 0xffffu)); xv[7] = bf2f((bfraw)(raw.w >> 16));
}
// DT=0: bf16 input, DT=1: fp32 input
template<int DT> __device__ __forceinline__ float ldx(const void* p, size_t i) {
    if (DT) return ((const float*)p)[i];
    return bf2f(((const bfraw*)p)[i]);
}
template<int DT> __device__ __forceinline__ void ld8(const void* p, size_t i, float* o) {
    if (DT) {
        const float4* q = (const float4*)((const float*)p + i);
        float4 a = q[0], b = q[1];
        o[0]=a.x;o[1]=a.y;o[2]=a.z;o[3]=a.w;o[4]=b.x;o[5]=b.y;o[6]=b.z;o[7]=b.w;
    } else {
        uint4 raw = *(const uint4*)((const bfraw*)p + i);
        unpack8(raw, o);
    }
}
template<int DT> __device__ __forceinline__ void ldx2(const void* p, size_t i, float* o) {
    if (DT) {
        float2 v = *(const float2*)((const float*)p + i);
        o[0] = v.x; o[1] = v.y;
    } else {
        uint32_t r = *(const uint32_t*)((const bfraw*)p + i);
        o[0] = bf2f((bfraw)(r & 0xffffu)); o[1] = bf2f((bfraw)(r >> 16));
    }
}

// ---- detect dtype + prep weights (merged, 1 block) ----------------------------
// Fused weight layout wkqT[c][0..31]=Wk col c, [32..63]=Wq col c. bkq likewise.
template<int DT> __device__ __forceinline__ void prep_body(
    const void* Wq, const void* bq, const void* Wk, const void* bk,
    float* wkqT, float* bkq) {
    int tid = threadIdx.x;
    for (int i = tid; i < CQK*NC; i += 256) {
        int m = i >> 8, c = i & 255;
        wkqT[c*64 + m]      = ldx<DT>(Wk, i);
        wkqT[c*64 + 32 + m] = ldx<DT>(Wq, i);
    }
    if (tid < CQK)      bkq[tid]      = ldx<DT>(bk, tid);
    else if (tid < 64)  bkq[tid]      = ldx<DT>(bq, tid - 32);
}
__global__ __launch_bounds__(256) void detprep_kernel(
    const bfraw* __restrict__ xr, const void* Wq, const void* bq,
    const void* Wk, const void* bk,
    int* __restrict__ flag, float* __restrict__ wkqT, float* __restrict__ bkq) {
    __shared__ int cnt, ez, fl_s;
    int tid = threadIdx.x;
    if (tid == 0) { cnt = 0; ez = 0; }
    __syncthreads();
    int crazy = 0, evenzero = 0;
    for (int i = tid; i < 2048; i += 256) {
        bfraw u = xr[i];
        float v = bf2f(u);
        float a = fabsf(v);
        if (!(a <= 1e10f) || (v != 0.f && a < 1e-10f)) crazy++;
        if ((i & 1) == 0 && u == 0) evenzero++;
    }
    atomicAdd(&cnt, crazy);
    atomicAdd(&ez, evenzero);
    __syncthreads();
    if (tid == 0) { fl_s = (cnt > 64 || ez > 900) ? 1 : 0; flag[0] = fl_s; }
    __syncthreads();
    if (fl_s) prep_body<1>(Wq, bq, Wk, bk, wkqT, bkq);
    else      prep_body<0>(Wq, bq, Wk, bk, wkqT, bkq);
}

// ---- pass 1: K+Q proj, normalize; Qn -> global; partial S / x_sum / ksum ------
// Grid: NB*PB blocks, one 128-pixel tile each. 256 threads:
//   phase A: thread t = (pair = t&63 -> pixels 2*pair,2*pair+1 ; g = t>>6 ->
//            m-slice [16g,16g+16)). Each thread covers all 256 channels.
//   phase B: thread = channel.
template<int DT> __device__ __forceinline__ void pass1_body(
    const void* __restrict__ x, const float* __restrict__ wkqT,
    const float* __restrict__ bkq, float4* __restrict__ qn4,
    float* __restrict__ partial, float (*kn_s)[36], float* __restrict__ ss_s) {
    const int tid  = threadIdx.x;
    const int b    = blockIdx.x >> 7;          // / PB
    const int j    = blockIdx.x & (PB - 1);
    const int n0   = j * TN;
    const int pair = tid & 63;
    const int g    = tid >> 6;                 // wave index == m-group
    const size_t xb = (size_t)b * NC * NPIX;

    // ---- phase A: project 2 pixels x 16 outputs over 256 channels ----
    float kq0[16], kq1[16];
    #pragma unroll
    for (int i = 0; i < 16; ++i) {
        float bb = bkq[g*16 + i];
        kq0[i] = bb; kq1[i] = bb;
    }
    {
        const size_t pix0 = xb + (size_t)n0 + 2*pair;
        for (int c0 = 0; c0 < NC; c0 += 8) {
            float xv[8][2];
            #pragma unroll
            for (int jj = 0; jj < 8; ++jj)
                ldx2<DT>(x, pix0 + (size_t)(c0 + jj) * NPIX, xv[jj]);
            #pragma unroll
            for (int jj = 0; jj < 8; ++jj) {
                const float4* w = (const float4*)(wkqT + (c0 + jj)*64 + g*16); // wave-uniform
                #pragma unroll
                for (int m4 = 0; m4 < 4; ++m4) {
                    float4 wv = w[m4];
                    kq0[m4*4+0] += wv.x * xv[jj][0]; kq0[m4*4+1] += wv.y * xv[jj][0];
                    kq0[m4*4+2] += wv.z * xv[jj][0]; kq0[m4*4+3] += wv.w * xv[jj][0];
                    kq1[m4*4+0] += wv.x * xv[jj][1]; kq1[m4*4+1] += wv.y * xv[jj][1];
                    kq1[m4*4+2] += wv.z * xv[jj][1]; kq1[m4*4+3] += wv.w * xv[jj][1];
                }
            }
        }
    }

    // cross-group sum-of-squares reduce (K = groups 0+1, Q = groups 2+3)
    float ss0 = 0.f, ss1 = 0.f;
    #pragma unroll
    for (int i = 0; i < 16; ++i) { ss0 += kq0[i]*kq0[i]; ss1 += kq1[i]*kq1[i]; }
    ss_s[(g*64 + pair)*2 + 0] = ss0;
    ss_s[(g*64 + pair)*2 + 1] = ss1;
    __syncthreads();   // barrier A

    if (g < 2) {
        float inv0 = rsqrtf(ss_s[(0*64+pair)*2+0] + ss_s[(1*64+pair)*2+0]);
        float inv1 = rsqrtf(ss_s[(0*64+pair)*2+1] + ss_s[(1*64+pair)*2+1]);
        float* r0 = &kn_s[2*pair  ][g*16];
        float* r1 = &kn_s[2*pair+1][g*16];
        #pragma unroll
        for (int m4 = 0; m4 < 4; ++m4) {
            float4 v0, v1;
            v0.x = kq0[m4*4+0]*inv0; v0.y = kq0[m4*4+1]*inv0;
            v0.z = kq0[m4*4+2]*inv0; v0.w = kq0[m4*4+3]*inv0;
            v1.x = kq1[m4*4+0]*inv1; v1.y = kq1[m4*4+1]*inv1;
            v1.z = kq1[m4*4+2]*inv1; v1.w = kq1[m4*4+3]*inv1;
            *((float4*)&r0[m4*4]) = v0;
            *((float4*)&r1[m4*4]) = v1;
        }
    } else {
        float inv0 = rsqrtf(ss_s[(2*64+pair)*2+0] + ss_s[(3*64+pair)*2+0]);
        float inv1 = rsqrtf(ss_s[(2*64+pair)*2+1] + ss_s[(3*64+pair)*2+1]);
        // Qn -> global, [b][m4][n] float4, fully coalesced (2 consecutive f4/lane)
        float4* qp = qn4 + (size_t)b * 8 * NPIX + (n0 + 2*pair);
        const int g2 = g - 2;
        #pragma unroll
        for (int m4 = 0; m4 < 4; ++m4) {
            float4 v0, v1;
            v0.x = kq0[m4*4+0]*inv0; v0.y = kq0[m4*4+1]*inv0;
            v0.z = kq0[m4*4+2]*inv0; v0.w = kq0[m4*4+3]*inv0;
            v1.x = kq1[m4*4+0]*inv1; v1.y = kq1[m4*4+1]*inv1;
            v1.z = kq1[m4*4+2]*inv1; v1.w = kq1[m4*4+3]*inv1;
            qp[(size_t)(g2*4 + m4) * NPIX]     = v0;
            qp[(size_t)(g2*4 + m4) * NPIX + 1] = v1;
        }
    }
    __syncthreads();   // barrier B: kn_s ready

    // ---- phase B: S[m][c=tid] += sum_k kn[k][m] * x[tid][n0+k] ----
    float sacc[CQK];
    #pragma unroll
    for (int m = 0; m < CQK; ++m) sacc[m] = 0.f;
    float xsacc = 0.f;
    const size_t rowb = xb + (size_t)tid * NPIX + n0;
    for (int k0 = 0; k0 < TN; k0 += 8) {
        float xv[8]; ld8<DT>(x, rowb + k0, xv);
        #pragma unroll
        for (int kk = 0; kk < 8; ++kk) {
            const float4* kr = (const float4*)&kn_s[k0+kk][0];  // broadcast
            float xvk = xv[kk];
            #pragma unroll
            for (int m4 = 0; m4 < 8; ++m4) {
                float4 a = kr[m4];
                sacc[m4*4+0] += a.x*xvk; sacc[m4*4+1] += a.y*xvk;
                sacc[m4*4+2] += a.z*xvk; sacc[m4*4+3] += a.w*xvk;
            }
            xsacc += xvk;
        }
    }

    // parallel ksum: thread (m = tid&31, h = tid>>5) sums 16 rows; reuse ss_s
    // (safe: last ss_s reads were before barrier B)
    {
        const int m_ = tid & 31, h_ = tid >> 5;
        float kp = 0.f;
        #pragma unroll
        for (int t = 0; t < 16; ++t) kp += kn_s[h_*16 + t][m_];
        ss_s[h_*32 + m_] = kp;
    }
    __syncthreads();   // barrier C

    const size_t base = (size_t)blockIdx.x * PARTF;
    #pragma unroll
    for (int m = 0; m < CQK; ++m) partial[base + m*NC + tid] = sacc[m];
    partial[base + CQK*NC + tid] = xsacc;
    if (tid < CQK) {
        float ks = 0.f;
        #pragma unroll
        for (int h = 0; h < 8; ++h) ks += ss_s[h*32 + tid];
        partial[base + CQK*NC + NC + tid] = ks;
    }
}
__global__ __launch_bounds__(256, 4) void pass1_kernel(
    const void* __restrict__ x, const float* __restrict__ wkqT,
    const float* __restrict__ bkq, float4* __restrict__ qn4,
    float* __restrict__ partial, const int* __restrict__ flag) {
    __shared__ __align__(16) float kn_s[TN][36];
    __shared__ float ss_s[4*64*2];   // also reused as [8][32] ksum scratch
    if (flag[0]) pass1_body<1>(x, wkqT, bkq, qn4, partial, kn_s, ss_s);
    else         pass1_body<0>(x, wkqT, bkq, qn4, partial, kn_s, ss_s);
}

// ---- pass 1.5: reduce partials; matrix^T [b][c][32], value_sum, k_sum ---------
template<int DT> __device__ __forceinline__ float dot256(const void* Wv, int row,
                                                         const float* sh) {
    float r = 0.f;
    for (int c0 = 0; c0 < NC; c0 += 8) {
        float xv[8]; ld8<DT>(Wv, (size_t)row * NC + c0, xv);
        #pragma unroll
        for (int i = 0; i < 8; ++i) r += xv[i] * sh[c0+i];
    }
    return r;
}
template<int DT> __device__ __forceinline__ void pass15_body(
    const float* __restrict__ partial, const void* __restrict__ Wv,
    const void* __restrict__ bv, float* __restrict__ matT,
    float* __restrict__ vsum, float* __restrict__ ksum, float* sh) {
    int tid = threadIdx.x;
    int b = blockIdx.x / 33, m = blockIdx.x % 33;
    const float* pb_ = partial + (size_t)b * PB * PARTF;

    if (m < CQK) {
        float acc = 0.f;
        for (int p = 0; p < PB; ++p) acc += pb_[(size_t)p*PARTF + m*NC + tid];
        sh[tid] = acc;
        float ks = 0.f;
        for (int p = 0; p < PB; ++p) ks += pb_[(size_t)p*PARTF + CQK*NC + NC + m];
        __syncthreads();
        float r = dot256<DT>(Wv, tid, sh);
        matT[((size_t)b*NC + tid)*CQK + m] = r + ldx<DT>(bv, tid) * ks;
        if (tid == 0) ksum[b*CQK + m] = ks + EPSV;
    } else {
        float acc = 0.f;
        for (int p = 0; p < PB; ++p) acc += pb_[(size_t)p*PARTF + CQK*NC + tid];
        sh[tid] = acc;
        __syncthreads();
        float r = dot256<DT>(Wv, tid, sh);
        vsum[b*NC + tid] = r + (float)NPIX * ldx<DT>(bv, tid);
    }
}
__global__ __launch_bounds__(256) void pass15_kernel(
    const float* __restrict__ partial, const void* __restrict__ Wv,
    const void* __restrict__ bv, float* __restrict__ matT,
    float* __restrict__ vsum, float* __restrict__ ksum,
    const int* __restrict__ flag) {
    __shared__ float sh[NC];
    if (flag[0]) pass15_body<1>(partial, Wv, bv, matT, vsum, ksum, sh);
    else         pass15_body<0>(partial, Wv, bv, matT, vsum, ksum, sh);
}

// ---- pass 2: epilogue. 2 pixels/thread, float2 loads/stores. ------------------
// grid = NB * 32 * 4 : (b, 512-pixel tile, 64-channel chunk)
template<int DT> __device__ __forceinline__ void pass2_body(
    const void* __restrict__ x, const float4* __restrict__ qn4,
    const float* __restrict__ ksum, const float* __restrict__ matT,
    const float* __restrict__ vsum, const void* __restrict__ gamma,
    float* __restrict__ out) {
    int tid = threadIdx.x;
    int bx = blockIdx.x;
    int cs = bx & 3, tile = (bx >> 2) & 31, b = bx >> 7;
    int p0 = tile * 512 + 2 * tid;

    float q0[CQK], q1[CQK];
    const float4* qp = qn4 + (size_t)b * 8 * NPIX + p0;
    #pragma unroll
    for (int m4 = 0; m4 < 8; ++m4) {
        float4 a = qp[(size_t)m4 * NPIX];
        float4 c = qp[(size_t)m4 * NPIX + 1];
        q0[m4*4+0]=a.x; q0[m4*4+1]=a.y; q0[m4*4+2]=a.z; q0[m4*4+3]=a.w;
        q1[m4*4+0]=c.x; q1[m4*4+1]=c.y; q1[m4*4+2]=c.z; q1[m4*4+3]=c.w;
    }
    const float* ksb = ksum + b*CQK;   // uniform
    float dot0 = 0.f, dot1 = 0.f;
    #pragma unroll
    for (int m = 0; m < CQK; ++m) {
        float k = ksb[m];
        dot0 += q0[m] * k; dot1 += q1[m] * k;
    }
    float gm_ = ldx<DT>(gamma, 0);
    float gt0 = gm_ / ((float)NPIX + dot0);
    float gt1 = gm_ / ((float)NPIX + dot1);

    int c0 = cs * 64;
    const float* mb = matT + ((size_t)b*NC + c0)*CQK;  // uniform rows
    const float* vb = vsum + (size_t)b*NC + c0;
    size_t xbase = (size_t)b*NC*NPIX + (size_t)c0*NPIX + p0;

    for (int ci = 0; ci < 64; ci += 4) {
        float xv[4][2];
        #pragma unroll
        for (int u = 0; u < 4; ++u)
            ldx2<DT>(x, xbase + (size_t)(ci+u)*NPIX, xv[u]);
        #pragma unroll
        for (int u = 0; u < 4; ++u) {
            float r0 = vb[ci+u], r1 = r0;
            const float4* mr = (const float4*)(mb + (ci+u)*CQK);  // uniform
            #pragma unroll
            for (int m4 = 0; m4 < 8; ++m4) {
                float4 a = mr[m4];
                r0 += q0[m4*4+0]*a.x + q0[m4*4+1]*a.y + q0[m4*4+2]*a.z + q0[m4*4+3]*a.w;
                r1 += q1[m4*4+0]*a.x + q1[m4*4+1]*a.y + q1[m4*4+2]*a.z + q1[m4*4+3]*a.w;
            }
            float2 o;
            o.x = xv[u][0] + gt0*r0;
            o.y = xv[u][1] + gt1*r1;
            *reinterpret_cast<float2*>(out + xbase + (size_t)(ci+u)*NPIX) = o;
        }
    }
}
__global__ __launch_bounds__(256, 4) void pass2_kernel(
    const void* __restrict__ x, const float4* __restrict__ qn4,
    const float* __restrict__ ksum, const float* __restrict__ matT,
    const float* __restrict__ vsum, const void* __restrict__ gamma,
    float* __restrict__ out, const int* __restrict__ flag) {
    if (flag[0]) pass2_body<1>(x, qn4, ksum, matT, vsum, gamma, out);
    else         pass2_body<0>(x, qn4, ksum, matT, vsum, gamma, out);
}

// ---- host ----------------------------------------------------------------------
extern "C" void kernel_launch(void* const* d_in, const int* in_sizes, int n_in,
                              void* d_out, int out_size, void* d_ws, size_t ws_size,
                              hipStream_t stream)
{
    const void* x  = d_in[0];
    const void* Wq = d_in[1];
    const void* bq = d_in[2];
    const void* Wk = d_in[3];
    const void* bk = d_in[4];
    const void* Wv = d_in[5];
    const void* bv = d_in[6];
    const void* gm = d_in[7];
    float* out = (float*)d_out;

    float* ws = (float*)d_ws;
    int*   flag = (int*)ws;             // 16 floats reserved
    float* wkqT = ws + 16;              // 16384
    float* bkq  = wkqT + 64*NC;         // 64
    float* matT = bkq + 64;             // NB*NC*CQK = 65536
    float* vsum = matT + NB*NC*CQK;     // 2048
    float* ksum = vsum + NB*NC;         // 256
    float* qn4f = ksum + NB*CQK;        // NB*8*NPIX*4 = 4194304 (16B-aligned)
    float* partial_ws = qn4f + (size_t)NB*8*NPIX*4;

    // Partial S scratch: NB*PB*PARTF floats = 34.7 MB. Prefer ws (known-good
    // placement from the 489us baseline, which used >= 34.5 MB of ws). Only
    // if ws can't hold it, alias into d_out (fully rewritten by pass2;
    // stream-ordered so pass15 consumes it first).
    size_t fixedf = (size_t)(partial_ws - ws);
    size_t needb  = (fixedf + (size_t)NB*PB*PARTF) * sizeof(float);
    float* partial = (needb <= ws_size) ? partial_ws : (float*)d_out;

    hipLaunchKernelGGL(detprep_kernel, dim3(1), dim3(256), 0, stream,
                       (const bfraw*)x, Wq, bq, Wk, bk, flag, wkqT, bkq);
    hipLaunchKernelGGL(pass1_kernel, dim3(NB*PB), dim3(256), 0, stream,
                       x, wkqT, bkq, (float4*)qn4f, partial, flag);
    hipLaunchKernelGGL(pass15_kernel, dim3(NB*33), dim3(256), 0, stream,
                       partial, Wv, bv, matT, vsum, ksum, flag);
    hipLaunchKernelGGL(pass2_kernel, dim3(NB*32*4), dim3(256), 0, stream,
                       x, (const float4*)qn4f, ksum, matT, vsum, gm, out, flag);
}

// Round 3
// 633.179 us; speedup vs baseline: 1.2478x; 1.2478x over previous
//
#include <hip/hip_runtime.h>
#include <stdint.h>

// PositionLinearAttention on MI355X. B=8, C=256, Cqk=32, N=16384.
// R7 == R6 with the launch-bounds spill bug fixed: __launch_bounds__(256, 4)
// made hipcc clamp pass1/pass2 to the 64-VGPR bucket and spill q0/q1/kq to
// scratch (rocprof R6: pass2 VGPR=64, VALUBusy 6%, 1.26 GB moved vs 335 MB
// floor -> scratch thrash through L2). Plain __launch_bounds__(256) lets the
// compiler allocate ~100 VGPR; the hardware bucket is then 4 waves/SIMD =
// 4 blocks/CU -- the occupancy we wanted, without spills.
//
// Reformulation (V never materialized):
//   S[b][m][c']   = sum_n Kn[b][m][n] * x[b][c'][n]
//   matrix[b][m][c] = sum_c' Wv[c][c'] S[b][m][c'] + bv[c]*ksraw[b][m]
//   value_sum[b][c] = sum_c' Wv[c][c'] x_sum[b][c'] + N*bv[c]
//   tailor[n] = 1/(N + Qn[n]·(ksraw+EPS))
//   out[b][c][n] = x + gamma*tailor[n]*(value_sum[c] + Qn[n]·matrix[:,c])

#define NB 8
#define NC 256
#define CQK 32
#define NPIX 16384
#define TN 128                       // pixels per pass1 tile
#define PB 128                       // pass1 blocks per batch = NPIX/TN
#define PARTF (CQK*NC + NC + CQK)    // 8480 floats per partial block
#define EPSV 1e-6f

typedef unsigned short bfraw;

__device__ __forceinline__ float bf2f(bfraw u) {
    union { uint32_t i; float f; } v; v.i = ((uint32_t)u) << 16; return v.f;
}
__device__ __forceinline__ void unpack8(uint4 raw, float* xv) {
    xv[0] = bf2f((bfraw)(raw.x & 0xffffu)); xv[1] = bf2f((bfraw)(raw.x >> 16));
    xv[2] = bf2f((bfraw)(raw.y & 0xffffu)); xv[3] = bf2f((bfraw)(raw.y >> 16));
    xv[4] = bf2f((bfraw)(raw.z & 0xffffu)); xv[5] = bf2f((bfraw)(raw.z >> 16));
    xv[6] = bf2f((bfraw)(raw.w & 0xffffu)); xv[7] = bf2f((bfraw)(raw.w >> 16));
}
// DT=0: bf16 input, DT=1: fp32 input
template<int DT> __device__ __forceinline__ float ldx(const void* p, size_t i) {
    if (DT) return ((const float*)p)[i];
    return bf2f(((const bfraw*)p)[i]);
}
template<int DT> __device__ __forceinline__ void ld8(const void* p, size_t i, float* o) {
    if (DT) {
        const float4* q = (const float4*)((const float*)p + i);
        float4 a = q[0], b = q[1];
        o[0]=a.x;o[1]=a.y;o[2]=a.z;o[3]=a.w;o[4]=b.x;o[5]=b.y;o[6]=b.z;o[7]=b.w;
    } else {
        uint4 raw = *(const uint4*)((const bfraw*)p + i);
        unpack8(raw, o);
    }
}
template<int DT> __device__ __forceinline__ void ldx2(const void* p, size_t i, float* o) {
    if (DT) {
        float2 v = *(const float2*)((const float*)p + i);
        o[0] = v.x; o[1] = v.y;
    } else {
        uint32_t r = *(const uint32_t*)((const bfraw*)p + i);
        o[0] = bf2f((bfraw)(r & 0xffffu)); o[1] = bf2f((bfraw)(r >> 16));
    }
}

// ---- detect dtype + prep weights (merged, 1 block) ----------------------------
// Fused weight layout wkqT[c][0..31]=Wk col c, [32..63]=Wq col c. bkq likewise.
template<int DT> __device__ __forceinline__ void prep_body(
    const void* Wq, const void* bq, const void* Wk, const void* bk,
    float* wkqT, float* bkq) {
    int tid = threadIdx.x;
    for (int i = tid; i < CQK*NC; i += 256) {
        int m = i >> 8, c = i & 255;
        wkqT[c*64 + m]      = ldx<DT>(Wk, i);
        wkqT[c*64 + 32 + m] = ldx<DT>(Wq, i);
    }
    if (tid < CQK)      bkq[tid]      = ldx<DT>(bk, tid);
    else if (tid < 64)  bkq[tid]      = ldx<DT>(bq, tid - 32);
}
__global__ __launch_bounds__(256) void detprep_kernel(
    const bfraw* __restrict__ xr, const void* Wq, const void* bq,
    const void* Wk, const void* bk,
    int* __restrict__ flag, float* __restrict__ wkqT, float* __restrict__ bkq) {
    __shared__ int cnt, ez, fl_s;
    int tid = threadIdx.x;
    if (tid == 0) { cnt = 0; ez = 0; }
    __syncthreads();
    int crazy = 0, evenzero = 0;
    for (int i = tid; i < 2048; i += 256) {
        bfraw u = xr[i];
        float v = bf2f(u);
        float a = fabsf(v);
        if (!(a <= 1e10f) || (v != 0.f && a < 1e-10f)) crazy++;
        if ((i & 1) == 0 && u == 0) evenzero++;
    }
    atomicAdd(&cnt, crazy);
    atomicAdd(&ez, evenzero);
    __syncthreads();
    if (tid == 0) { fl_s = (cnt > 64 || ez > 900) ? 1 : 0; flag[0] = fl_s; }
    __syncthreads();
    if (fl_s) prep_body<1>(Wq, bq, Wk, bk, wkqT, bkq);
    else      prep_body<0>(Wq, bq, Wk, bk, wkqT, bkq);
}

// ---- pass 1: K+Q proj, normalize; Qn -> global; partial S / x_sum / ksum ------
// Grid: NB*PB blocks, one 128-pixel tile each. 256 threads:
//   phase A: thread t = (pair = t&63 -> pixels 2*pair,2*pair+1 ; g = t>>6 ->
//            m-slice [16g,16g+16)). Each thread covers all 256 channels.
//   phase B: thread = channel.
template<int DT> __device__ __forceinline__ void pass1_body(
    const void* __restrict__ x, const float* __restrict__ wkqT,
    const float* __restrict__ bkq, float4* __restrict__ qn4,
    float* __restrict__ partial, float (*kn_s)[36], float* __restrict__ ss_s) {
    const int tid  = threadIdx.x;
    const int b    = blockIdx.x >> 7;          // / PB
    const int j    = blockIdx.x & (PB - 1);
    const int n0   = j * TN;
    const int pair = tid & 63;
    const int g    = tid >> 6;                 // wave index == m-group
    const size_t xb = (size_t)b * NC * NPIX;

    // ---- phase A: project 2 pixels x 16 outputs over 256 channels ----
    float kq0[16], kq1[16];
    #pragma unroll
    for (int i = 0; i < 16; ++i) {
        float bb = bkq[g*16 + i];
        kq0[i] = bb; kq1[i] = bb;
    }
    {
        const size_t pix0 = xb + (size_t)n0 + 2*pair;
        for (int c0 = 0; c0 < NC; c0 += 8) {
            float xv[8][2];
            #pragma unroll
            for (int jj = 0; jj < 8; ++jj)
                ldx2<DT>(x, pix0 + (size_t)(c0 + jj) * NPIX, xv[jj]);
            #pragma unroll
            for (int jj = 0; jj < 8; ++jj) {
                const float4* w = (const float4*)(wkqT + (c0 + jj)*64 + g*16); // wave-uniform
                #pragma unroll
                for (int m4 = 0; m4 < 4; ++m4) {
                    float4 wv = w[m4];
                    kq0[m4*4+0] += wv.x * xv[jj][0]; kq0[m4*4+1] += wv.y * xv[jj][0];
                    kq0[m4*4+2] += wv.z * xv[jj][0]; kq0[m4*4+3] += wv.w * xv[jj][0];
                    kq1[m4*4+0] += wv.x * xv[jj][1]; kq1[m4*4+1] += wv.y * xv[jj][1];
                    kq1[m4*4+2] += wv.z * xv[jj][1]; kq1[m4*4+3] += wv.w * xv[jj][1];
                }
            }
        }
    }

    // cross-group sum-of-squares reduce (K = groups 0+1, Q = groups 2+3)
    float ss0 = 0.f, ss1 = 0.f;
    #pragma unroll
    for (int i = 0; i < 16; ++i) { ss0 += kq0[i]*kq0[i]; ss1 += kq1[i]*kq1[i]; }
    ss_s[(g*64 + pair)*2 + 0] = ss0;
    ss_s[(g*64 + pair)*2 + 1] = ss1;
    __syncthreads();   // barrier A

    if (g < 2) {
        float inv0 = rsqrtf(ss_s[(0*64+pair)*2+0] + ss_s[(1*64+pair)*2+0]);
        float inv1 = rsqrtf(ss_s[(0*64+pair)*2+1] + ss_s[(1*64+pair)*2+1]);
        float* r0 = &kn_s[2*pair  ][g*16];
        float* r1 = &kn_s[2*pair+1][g*16];
        #pragma unroll
        for (int m4 = 0; m4 < 4; ++m4) {
            float4 v0, v1;
            v0.x = kq0[m4*4+0]*inv0; v0.y = kq0[m4*4+1]*inv0;
            v0.z = kq0[m4*4+2]*inv0; v0.w = kq0[m4*4+3]*inv0;
            v1.x = kq1[m4*4+0]*inv1; v1.y = kq1[m4*4+1]*inv1;
            v1.z = kq1[m4*4+2]*inv1; v1.w = kq1[m4*4+3]*inv1;
            *((float4*)&r0[m4*4]) = v0;
            *((float4*)&r1[m4*4]) = v1;
        }
    } else {
        float inv0 = rsqrtf(ss_s[(2*64+pair)*2+0] + ss_s[(3*64+pair)*2+0]);
        float inv1 = rsqrtf(ss_s[(2*64+pair)*2+1] + ss_s[(3*64+pair)*2+1]);
        // Qn -> global, [b][m4][n] float4, fully coalesced (2 consecutive f4/lane)
        float4* qp = qn4 + (size_t)b * 8 * NPIX + (n0 + 2*pair);
        const int g2 = g - 2;
        #pragma unroll
        for (int m4 = 0; m4 < 4; ++m4) {
            float4 v0, v1;
            v0.x = kq0[m4*4+0]*inv0; v0.y = kq0[m4*4+1]*inv0;
            v0.z = kq0[m4*4+2]*inv0; v0.w = kq0[m4*4+3]*inv0;
            v1.x = kq1[m4*4+0]*inv1; v1.y = kq1[m4*4+1]*inv1;
            v1.z = kq1[m4*4+2]*inv1; v1.w = kq1[m4*4+3]*inv1;
            qp[(size_t)(g2*4 + m4) * NPIX]     = v0;
            qp[(size_t)(g2*4 + m4) * NPIX + 1] = v1;
        }
    }
    __syncthreads();   // barrier B: kn_s ready

    // ---- phase B: S[m][c=tid] += sum_k kn[k][m] * x[tid][n0+k] ----
    float sacc[CQK];
    #pragma unroll
    for (int m = 0; m < CQK; ++m) sacc[m] = 0.f;
    float xsacc = 0.f;
    const size_t rowb = xb + (size_t)tid * NPIX + n0;
    for (int k0 = 0; k0 < TN; k0 += 8) {
        float xv[8]; ld8<DT>(x, rowb + k0, xv);
        #pragma unroll
        for (int kk = 0; kk < 8; ++kk) {
            const float4* kr = (const float4*)&kn_s[k0+kk][0];  // broadcast
            float xvk = xv[kk];
            #pragma unroll
            for (int m4 = 0; m4 < 8; ++m4) {
                float4 a = kr[m4];
                sacc[m4*4+0] += a.x*xvk; sacc[m4*4+1] += a.y*xvk;
                sacc[m4*4+2] += a.z*xvk; sacc[m4*4+3] += a.w*xvk;
            }
            xsacc += xvk;
        }
    }

    // parallel ksum: thread (m = tid&31, h = tid>>5) sums 16 rows; reuse ss_s
    // (safe: last ss_s reads were before barrier B)
    {
        const int m_ = tid & 31, h_ = tid >> 5;
        float kp = 0.f;
        #pragma unroll
        for (int t = 0; t < 16; ++t) kp += kn_s[h_*16 + t][m_];
        ss_s[h_*32 + m_] = kp;
    }
    __syncthreads();   // barrier C

    const size_t base = (size_t)blockIdx.x * PARTF;
    #pragma unroll
    for (int m = 0; m < CQK; ++m) partial[base + m*NC + tid] = sacc[m];
    partial[base + CQK*NC + tid] = xsacc;
    if (tid < CQK) {
        float ks = 0.f;
        #pragma unroll
        for (int h = 0; h < 8; ++h) ks += ss_s[h*32 + tid];
        partial[base + CQK*NC + NC + tid] = ks;
    }
}
__global__ __launch_bounds__(256) void pass1_kernel(
    const void* __restrict__ x, const float* __restrict__ wkqT,
    const float* __restrict__ bkq, float4* __restrict__ qn4,
    float* __restrict__ partial, const int* __restrict__ flag) {
    __shared__ __align__(16) float kn_s[TN][36];
    __shared__ float ss_s[4*64*2];   // also reused as [8][32] ksum scratch
    if (flag[0]) pass1_body<1>(x, wkqT, bkq, qn4, partial, kn_s, ss_s);
    else         pass1_body<0>(x, wkqT, bkq, qn4, partial, kn_s, ss_s);
}

// ---- pass 1.5: reduce partials; matrix^T [b][c][32], value_sum, k_sum ---------
template<int DT> __device__ __forceinline__ float dot256(const void* Wv, int row,
                                                         const float* sh) {
    float r = 0.f;
    for (int c0 = 0; c0 < NC; c0 += 8) {
        float xv[8]; ld8<DT>(Wv, (size_t)row * NC + c0, xv);
        #pragma unroll
        for (int i = 0; i < 8; ++i) r += xv[i] * sh[c0+i];
    }
    return r;
}
template<int DT> __device__ __forceinline__ void pass15_body(
    const float* __restrict__ partial, const void* __restrict__ Wv,
    const void* __restrict__ bv, float* __restrict__ matT,
    float* __restrict__ vsum, float* __restrict__ ksum, float* sh) {
    int tid = threadIdx.x;
    int b = blockIdx.x / 33, m = blockIdx.x % 33;
    const float* pb_ = partial + (size_t)b * PB * PARTF;

    if (m < CQK) {
        float acc = 0.f;
        for (int p = 0; p < PB; ++p) acc += pb_[(size_t)p*PARTF + m*NC + tid];
        sh[tid] = acc;
        float ks = 0.f;
        for (int p = 0; p < PB; ++p) ks += pb_[(size_t)p*PARTF + CQK*NC + NC + m];
        __syncthreads();
        float r = dot256<DT>(Wv, tid, sh);
        matT[((size_t)b*NC + tid)*CQK + m] = r + ldx<DT>(bv, tid) * ks;
        if (tid == 0) ksum[b*CQK + m] = ks + EPSV;
    } else {
        float acc = 0.f;
        for (int p = 0; p < PB; ++p) acc += pb_[(size_t)p*PARTF + CQK*NC + tid];
        sh[tid] = acc;
        __syncthreads();
        float r = dot256<DT>(Wv, tid, sh);
        vsum[b*NC + tid] = r + (float)NPIX * ldx<DT>(bv, tid);
    }
}
__global__ __launch_bounds__(256) void pass15_kernel(
    const float* __restrict__ partial, const void* __restrict__ Wv,
    const void* __restrict__ bv, float* __restrict__ matT,
    float* __restrict__ vsum, float* __restrict__ ksum,
    const int* __restrict__ flag) {
    __shared__ float sh[NC];
    if (flag[0]) pass15_body<1>(partial, Wv, bv, matT, vsum, ksum, sh);
    else         pass15_body<0>(partial, Wv, bv, matT, vsum, ksum, sh);
}

// ---- pass 2: epilogue. 2 pixels/thread, float2 loads/stores. ------------------
// grid = NB * 32 * 4 : (b, 512-pixel tile, 64-channel chunk)
template<int DT> __device__ __forceinline__ void pass2_body(
    const void* __restrict__ x, const float4* __restrict__ qn4,
    const float* __restrict__ ksum, const float* __restrict__ matT,
    const float* __restrict__ vsum, const void* __restrict__ gamma,
    float* __restrict__ out) {
    int tid = threadIdx.x;
    int bx = blockIdx.x;
    int cs = bx & 3, tile = (bx >> 2) & 31, b = bx >> 7;
    int p0 = tile * 512 + 2 * tid;

    float q0[CQK], q1[CQK];
    const float4* qp = qn4 + (size_t)b * 8 * NPIX + p0;
    #pragma unroll
    for (int m4 = 0; m4 < 8; ++m4) {
        float4 a = qp[(size_t)m4 * NPIX];
        float4 c = qp[(size_t)m4 * NPIX + 1];
        q0[m4*4+0]=a.x; q0[m4*4+1]=a.y; q0[m4*4+2]=a.z; q0[m4*4+3]=a.w;
        q1[m4*4+0]=c.x; q1[m4*4+1]=c.y; q1[m4*4+2]=c.z; q1[m4*4+3]=c.w;
    }
    const float* ksb = ksum + b*CQK;   // uniform
    float dot0 = 0.f, dot1 = 0.f;
    #pragma unroll
    for (int m = 0; m < CQK; ++m) {
        float k = ksb[m];
        dot0 += q0[m] * k; dot1 += q1[m] * k;
    }
    float gm_ = ldx<DT>(gamma, 0);
    float gt0 = gm_ / ((float)NPIX + dot0);
    float gt1 = gm_ / ((float)NPIX + dot1);

    int c0 = cs * 64;
    const float* mb = matT + ((size_t)b*NC + c0)*CQK;  // uniform rows
    const float* vb = vsum + (size_t)b*NC + c0;
    size_t xbase = (size_t)b*NC*NPIX + (size_t)c0*NPIX + p0;

    for (int ci = 0; ci < 64; ci += 4) {
        float xv[4][2];
        #pragma unroll
        for (int u = 0; u < 4; ++u)
            ldx2<DT>(x, xbase + (size_t)(ci+u)*NPIX, xv[u]);
        #pragma unroll
        for (int u = 0; u < 4; ++u) {
            float r0 = vb[ci+u], r1 = r0;
            const float4* mr = (const float4*)(mb + (ci+u)*CQK);  // uniform
            #pragma unroll
            for (int m4 = 0; m4 < 8; ++m4) {
                float4 a = mr[m4];
                r0 += q0[m4*4+0]*a.x + q0[m4*4+1]*a.y + q0[m4*4+2]*a.z + q0[m4*4+3]*a.w;
                r1 += q1[m4*4+0]*a.x + q1[m4*4+1]*a.y + q1[m4*4+2]*a.z + q1[m4*4+3]*a.w;
            }
            float2 o;
            o.x = xv[u][0] + gt0*r0;
            o.y = xv[u][1] + gt1*r1;
            *reinterpret_cast<float2*>(out + xbase + (size_t)(ci+u)*NPIX) = o;
        }
    }
}
__global__ __launch_bounds__(256) void pass2_kernel(
    const void* __restrict__ x, const float4* __restrict__ qn4,
    const float* __restrict__ ksum, const float* __restrict__ matT,
    const float* __restrict__ vsum, const void* __restrict__ gamma,
    float* __restrict__ out, const int* __restrict__ flag) {
    if (flag[0]) pass2_body<1>(x, qn4, ksum, matT, vsum, gamma, out);
    else         pass2_body<0>(x, qn4, ksum, matT, vsum, gamma, out);
}

// ---- host ----------------------------------------------------------------------
extern "C" void kernel_launch(void* const* d_in, const int* in_sizes, int n_in,
                              void* d_out, int out_size, void* d_ws, size_t ws_size,
                              hipStream_t stream)
{
    const void* x  = d_in[0];
    const void* Wq = d_in[1];
    const void* bq = d_in[2];
    const void* Wk = d_in[3];
    const void* bk = d_in[4];
    const void* Wv = d_in[5];
    const void* bv = d_in[6];
    const void* gm = d_in[7];
    float* out = (float*)d_out;

    float* ws = (float*)d_ws;
    int*   flag = (int*)ws;             // 16 floats reserved
    float* wkqT = ws + 16;              // 16384
    float* bkq  = wkqT + 64*NC;         // 64
    float* matT = bkq + 64;             // NB*NC*CQK = 65536
    float* vsum = matT + NB*NC*CQK;     // 2048
    float* ksum = vsum + NB*NC;         // 256
    float* qn4f = ksum + NB*CQK;        // NB*8*NPIX*4 = 4194304 (16B-aligned)
    float* partial_ws = qn4f + (size_t)NB*8*NPIX*4;

    // Partial S scratch: NB*PB*PARTF floats = 34.7 MB. Prefer ws (known-good
    // placement from the 489us baseline, which used >= 34.5 MB of ws). Only
    // if ws can't hold it, alias into d_out (fully rewritten by pass2;
    // stream-ordered so pass15 consumes it first).
    size_t fixedf = (size_t)(partial_ws - ws);
    size_t needb  = (fixedf + (size_t)NB*PB*PARTF) * sizeof(float);
    float* partial = (needb <= ws_size) ? partial_ws : (float*)d_out;

    hipLaunchKernelGGL(detprep_kernel, dim3(1), dim3(256), 0, stream,
                       (const bfraw*)x, Wq, bq, Wk, bk, flag, wkqT, bkq);
    hipLaunchKernelGGL(pass1_kernel, dim3(NB*PB), dim3(256), 0, stream,
                       x, wkqT, bkq, (float4*)qn4f, partial, flag);
    hipLaunchKernelGGL(pass15_kernel, dim3(NB*33), dim3(256), 0, stream,
                       partial, Wv, bv, matT, vsum, ksum, flag);
    hipLaunchKernelGGL(pass2_kernel, dim3(NB*32*4), dim3(256), 0, stream,
                       x, (const float4*)qn4f, ksum, matT, vsum, gm, out, flag);
}

// Round 4
// 588.862 us; speedup vs baseline: 1.3417x; 1.0753x over previous
//
#include <hip/hip_runtime.h>
#include <stdint.h>

// PositionLinearAttention on MI355X. B=8, C=256, Cqk=32, N=16384.
// R8: LDS-staged pass1. R7 post-mortem: pass1 is latency*concurrency bound
// (0.75 TB/s, VALU 15%); both phases re-streamed x from HBM with long-stride
// access. Now each block stages a 64-pixel x-tile (256ch) into LDS once
// (x read from HBM exactly once in pass1), and both phase A (projection) and
// phase B (S accumulation) read LDS. 78 KB LDS -> 2 blocks/CU so staging of
// one block overlaps compute of the other. Each block does 2 tiles so the
// partial buffer stays at the proven 34.7 MB. pass2 = R7 structure with
// ci-step 8 (2x memory-level parallelism per thread).
//
// Reformulation (V never materialized):
//   S[b][m][c']   = sum_n Kn[b][m][n] * x[b][c'][n]
//   matrix[b][m][c] = sum_c' Wv[c][c'] S[b][m][c'] + bv[c]*ksraw[b][m]
//   value_sum[b][c] = sum_c' Wv[c][c'] x_sum[b][c'] + N*bv[c]
//   tailor[n] = 1/(N + Qn[n]·(ksraw+EPS))
//   out[b][c][n] = x + gamma*tailor[n]*(value_sum[c] + Qn[n]·matrix[:,c])

#define NB 8
#define NC 256
#define CQK 32
#define NPIX 16384
#define TNS 64                       // pixels per staged pass1 tile
#define PB 128                       // pass1 blocks per batch (each does 2 tiles)
#define PARTF (CQK*NC + NC + CQK)    // 8480 floats per partial block
#define EPSV 1e-6f
#define XROW 66                      // padded LDS row: 64 px + 2 pad
                                     //  phase A (lanes=px): consecutive banks, free
                                     //  phase B (lanes=c): bank=2c%32 -> 2-way, free

typedef unsigned short bfraw;

__device__ __forceinline__ float bf2f(bfraw u) {
    union { uint32_t i; float f; } v; v.i = ((uint32_t)u) << 16; return v.f;
}
__device__ __forceinline__ void unpack8(uint4 raw, float* xv) {
    xv[0] = bf2f((bfraw)(raw.x & 0xffffu)); xv[1] = bf2f((bfraw)(raw.x >> 16));
    xv[2] = bf2f((bfraw)(raw.y & 0xffffu)); xv[3] = bf2f((bfraw)(raw.y >> 16));
    xv[4] = bf2f((bfraw)(raw.z & 0xffffu)); xv[5] = bf2f((bfraw)(raw.z >> 16));
    xv[6] = bf2f((bfraw)(raw.w & 0xffffu)); xv[7] = bf2f((bfraw)(raw.w >> 16));
}
// DT=0: bf16 input, DT=1: fp32 input
template<int DT> __device__ __forceinline__ float ldx(const void* p, size_t i) {
    if (DT) return ((const float*)p)[i];
    return bf2f(((const bfraw*)p)[i]);
}
template<int DT> __device__ __forceinline__ void ld8(const void* p, size_t i, float* o) {
    if (DT) {
        const float4* q = (const float4*)((const float*)p + i);
        float4 a = q[0], b = q[1];
        o[0]=a.x;o[1]=a.y;o[2]=a.z;o[3]=a.w;o[4]=b.x;o[5]=b.y;o[6]=b.z;o[7]=b.w;
    } else {
        uint4 raw = *(const uint4*)((const bfraw*)p + i);
        unpack8(raw, o);
    }
}
template<int DT> __device__ __forceinline__ void ldx2(const void* p, size_t i, float* o) {
    if (DT) {
        float2 v = *(const float2*)((const float*)p + i);
        o[0] = v.x; o[1] = v.y;
    } else {
        uint32_t r = *(const uint32_t*)((const bfraw*)p + i);
        o[0] = bf2f((bfraw)(r & 0xffffu)); o[1] = bf2f((bfraw)(r >> 16));
    }
}

// ---- detect dtype + prep weights (merged, 1 block) ----------------------------
// Fused weight layout wkqT[c][0..31]=Wk col c, [32..63]=Wq col c. bkq likewise.
template<int DT> __device__ __forceinline__ void prep_body(
    const void* Wq, const void* bq, const void* Wk, const void* bk,
    float* wkqT, float* bkq) {
    int tid = threadIdx.x;
    for (int i = tid; i < CQK*NC; i += 256) {
        int m = i >> 8, c = i & 255;
        wkqT[c*64 + m]      = ldx<DT>(Wk, i);
        wkqT[c*64 + 32 + m] = ldx<DT>(Wq, i);
    }
    if (tid < CQK)      bkq[tid]      = ldx<DT>(bk, tid);
    else if (tid < 64)  bkq[tid]      = ldx<DT>(bq, tid - 32);
}
__global__ __launch_bounds__(256) void detprep_kernel(
    const bfraw* __restrict__ xr, const void* Wq, const void* bq,
    const void* Wk, const void* bk,
    int* __restrict__ flag, float* __restrict__ wkqT, float* __restrict__ bkq) {
    __shared__ int cnt, ez, fl_s;
    int tid = threadIdx.x;
    if (tid == 0) { cnt = 0; ez = 0; }
    __syncthreads();
    int crazy = 0, evenzero = 0;
    for (int i = tid; i < 2048; i += 256) {
        bfraw u = xr[i];
        float v = bf2f(u);
        float a = fabsf(v);
        if (!(a <= 1e10f) || (v != 0.f && a < 1e-10f)) crazy++;
        if ((i & 1) == 0 && u == 0) evenzero++;
    }
    atomicAdd(&cnt, crazy);
    atomicAdd(&ez, evenzero);
    __syncthreads();
    if (tid == 0) { fl_s = (cnt > 64 || ez > 900) ? 1 : 0; flag[0] = fl_s; }
    __syncthreads();
    if (fl_s) prep_body<1>(Wq, bq, Wk, bk, wkqT, bkq);
    else      prep_body<0>(Wq, bq, Wk, bk, wkqT, bkq);
}

// ---- pass 1: stage x tile in LDS; K+Q proj; Qn -> global; partial S ----------
// Grid NB*PB blocks, 256 threads. Each block: 2 tiles of TNS=64 pixels.
//   stage:   thread t -> row c = chunk + (t>>2), 16 floats at 16*(t&3)
//   phase A: thread t -> (px = t&63, qr = t>>6); qr in {0,1}: K half, {2,3}: Q
//   phase B: thread t -> channel c = t
template<int DT> __device__ __forceinline__ void pass1_body(
    const void* __restrict__ x, const float* __restrict__ wkqT,
    const float* __restrict__ bkq, float4* __restrict__ qn4,
    float* __restrict__ partial,
    float* __restrict__ x_s, float (*kn_s)[36], float* __restrict__ ss_s) {
    const int tid = threadIdx.x;
    const int b = blockIdx.x >> 7;             // / PB
    const int j = blockIdx.x & (PB - 1);
    const size_t xb = (size_t)b * NC * NPIX;
    const int px = tid & 63, qr = tid >> 6;
    const int sc = tid >> 2, sj = tid & 3;
    const int m_ = tid & 31, h_ = tid >> 5;

    float sacc[CQK];
    #pragma unroll
    for (int m = 0; m < CQK; ++m) sacc[m] = 0.f;
    float xsacc = 0.f, kreg = 0.f;

    for (int t2 = 0; t2 < 2; ++t2) {
        const int n0 = (j + t2 * PB) * TNS;

        __syncthreads();   // previous tile's x_s / kn_s readers done
        // ---- stage x[b][0:256][n0:n0+64] -> x_s (padded rows) ----
        for (int c0 = 0; c0 < NC; c0 += 64) {
            const int row = c0 + sc;
            const size_t g = xb + (size_t)row * NPIX + n0 + 16 * sj;
            float t16[16];
            ld8<DT>(x, g, t16);
            ld8<DT>(x, g + 8, t16 + 8);
            float* d = x_s + row * XROW + 16 * sj;
            #pragma unroll
            for (int w = 0; w < 8; ++w)
                *(float2*)(d + 2 * w) = make_float2(t16[2*w], t16[2*w+1]);
        }
        __syncthreads();

        // ---- phase A: kq[qr*16 .. +16) for pixel px over all 256 channels ----
        float kq[16];
        #pragma unroll
        for (int i = 0; i < 16; ++i) kq[i] = bkq[qr*16 + i];
        for (int c = 0; c < NC; c += 2) {
            float xa  = x_s[c * XROW + px];
            float xb2 = x_s[(c+1) * XROW + px];
            const float4* wA = (const float4*)(wkqT + c*64 + qr*16);      // wave-uniform
            const float4* wB = (const float4*)(wkqT + (c+1)*64 + qr*16);
            #pragma unroll
            for (int m4 = 0; m4 < 4; ++m4) {
                float4 wa = wA[m4], wb = wB[m4];
                kq[m4*4+0] += wa.x * xa; kq[m4*4+0] += wb.x * xb2;
                kq[m4*4+1] += wa.y * xa; kq[m4*4+1] += wb.y * xb2;
                kq[m4*4+2] += wa.z * xa; kq[m4*4+2] += wb.z * xb2;
                kq[m4*4+3] += wa.w * xa; kq[m4*4+3] += wb.w * xb2;
            }
        }
        float ss = 0.f;
        #pragma unroll
        for (int i = 0; i < 16; ++i) ss += kq[i] * kq[i];
        ss_s[qr*64 + px] = ss;
        __syncthreads();

        if (qr < 2) {
            float inv = rsqrtf(ss_s[px] + ss_s[64 + px]);
            float4* r = (float4*)&kn_s[px][qr*16];
            #pragma unroll
            for (int ii = 0; ii < 4; ++ii)
                r[ii] = make_float4(kq[ii*4+0]*inv, kq[ii*4+1]*inv,
                                    kq[ii*4+2]*inv, kq[ii*4+3]*inv);
        } else {
            float inv = rsqrtf(ss_s[128 + px] + ss_s[192 + px]);
            float4* qp = qn4 + (size_t)b * 8 * NPIX + (n0 + px);
            const int g2 = qr - 2;
            #pragma unroll
            for (int ii = 0; ii < 4; ++ii)
                qp[(size_t)(g2*4 + ii) * NPIX] =
                    make_float4(kq[ii*4+0]*inv, kq[ii*4+1]*inv,
                                kq[ii*4+2]*inv, kq[ii*4+3]*inv);
        }
        __syncthreads();   // kn_s ready

        // ---- phase B: S[m][c=tid] += sum_k kn[k][m] * x_s[c][k] ----
        {
            const float* xrow = x_s + tid * XROW;
            for (int k0 = 0; k0 < TNS; k0 += 2) {
                float2 xk = *(const float2*)(xrow + k0);
                const float4* kr0 = (const float4*)&kn_s[k0][0];     // broadcast
                const float4* kr1 = (const float4*)&kn_s[k0+1][0];
                #pragma unroll
                for (int m4 = 0; m4 < 8; ++m4) {
                    float4 a = kr0[m4], bb = kr1[m4];
                    sacc[m4*4+0] += a.x*xk.x; sacc[m4*4+0] += bb.x*xk.y;
                    sacc[m4*4+1] += a.y*xk.x; sacc[m4*4+1] += bb.y*xk.y;
                    sacc[m4*4+2] += a.z*xk.x; sacc[m4*4+2] += bb.z*xk.y;
                    sacc[m4*4+3] += a.w*xk.x; sacc[m4*4+3] += bb.w*xk.y;
                }
                xsacc += xk.x + xk.y;
            }
        }
        // ---- ksum partial for this tile: thread (m_, h_) sums 8 rows ----
        {
            float kp = 0.f;
            #pragma unroll
            for (int r = 0; r < 8; ++r) kp += kn_s[h_*8 + r][m_];
            kreg += kp;
        }
    }

    __syncthreads();                 // ss_s free for reuse as [8][32]
    ss_s[h_*32 + m_] = kreg;
    __syncthreads();

    const size_t base = (size_t)blockIdx.x * PARTF;
    #pragma unroll
    for (int m = 0; m < CQK; ++m) partial[base + m*NC + tid] = sacc[m];
    partial[base + CQK*NC + tid] = xsacc;
    if (tid < CQK) {
        float ks = 0.f;
        #pragma unroll
        for (int h = 0; h < 8; ++h) ks += ss_s[h*32 + tid];
        partial[base + CQK*NC + NC + tid] = ks;
    }
}
__global__ __launch_bounds__(256) void pass1_kernel(
    const void* __restrict__ x, const float* __restrict__ wkqT,
    const float* __restrict__ bkq, float4* __restrict__ qn4,
    float* __restrict__ partial, const int* __restrict__ flag) {
    __shared__ __align__(16) float x_s[NC * XROW];    // 67,584 B
    __shared__ __align__(16) float kn_s[TNS][36];     //  9,216 B
    __shared__ float ss_s[4 * 64];                    //  1,024 B (reused [8][32])
    if (flag[0]) pass1_body<1>(x, wkqT, bkq, qn4, partial, x_s, kn_s, ss_s);
    else         pass1_body<0>(x, wkqT, bkq, qn4, partial, x_s, kn_s, ss_s);
}

// ---- pass 1.5: reduce partials; matrix^T [b][c][32], value_sum, k_sum ---------
template<int DT> __device__ __forceinline__ float dot256(const void* Wv, int row,
                                                         const float* sh) {
    float r = 0.f;
    for (int c0 = 0; c0 < NC; c0 += 8) {
        float xv[8]; ld8<DT>(Wv, (size_t)row * NC + c0, xv);
        #pragma unroll
        for (int i = 0; i < 8; ++i) r += xv[i] * sh[c0+i];
    }
    return r;
}
template<int DT> __device__ __forceinline__ void pass15_body(
    const float* __restrict__ partial, const void* __restrict__ Wv,
    const void* __restrict__ bv, float* __restrict__ matT,
    float* __restrict__ vsum, float* __restrict__ ksum, float* sh) {
    int tid = threadIdx.x;
    int b = blockIdx.x / 33, m = blockIdx.x % 33;
    const float* pb_ = partial + (size_t)b * PB * PARTF;

    if (m < CQK) {
        float acc = 0.f;
        for (int p = 0; p < PB; ++p) acc += pb_[(size_t)p*PARTF + m*NC + tid];
        sh[tid] = acc;
        float ks = 0.f;
        for (int p = 0; p < PB; ++p) ks += pb_[(size_t)p*PARTF + CQK*NC + NC + m];
        __syncthreads();
        float r = dot256<DT>(Wv, tid, sh);
        matT[((size_t)b*NC + tid)*CQK + m] = r + ldx<DT>(bv, tid) * ks;
        if (tid == 0) ksum[b*CQK + m] = ks + EPSV;
    } else {
        float acc = 0.f;
        for (int p = 0; p < PB; ++p) acc += pb_[(size_t)p*PARTF + CQK*NC + tid];
        sh[tid] = acc;
        __syncthreads();
        float r = dot256<DT>(Wv, tid, sh);
        vsum[b*NC + tid] = r + (float)NPIX * ldx<DT>(bv, tid);
    }
}
__global__ __launch_bounds__(256) void pass15_kernel(
    const float* __restrict__ partial, const void* __restrict__ Wv,
    const void* __restrict__ bv, float* __restrict__ matT,
    float* __restrict__ vsum, float* __restrict__ ksum,
    const int* __restrict__ flag) {
    __shared__ float sh[NC];
    if (flag[0]) pass15_body<1>(partial, Wv, bv, matT, vsum, ksum, sh);
    else         pass15_body<0>(partial, Wv, bv, matT, vsum, ksum, sh);
}

// ---- pass 2: epilogue. 2 pixels/thread, ci-step 8 (8 float2 loads in flight) --
// grid = NB * 32 * 4 : (b, 512-pixel tile, 64-channel chunk)
template<int DT> __device__ __forceinline__ void pass2_body(
    const void* __restrict__ x, const float4* __restrict__ qn4,
    const float* __restrict__ ksum, const float* __restrict__ matT,
    const float* __restrict__ vsum, const void* __restrict__ gamma,
    float* __restrict__ out) {
    int tid = threadIdx.x;
    int bx = blockIdx.x;
    int cs = bx & 3, tile = (bx >> 2) & 31, b = bx >> 7;
    int p0 = tile * 512 + 2 * tid;

    float q0[CQK], q1[CQK];
    const float4* qp = qn4 + (size_t)b * 8 * NPIX + p0;
    #pragma unroll
    for (int m4 = 0; m4 < 8; ++m4) {
        float4 a = qp[(size_t)m4 * NPIX];
        float4 c = qp[(size_t)m4 * NPIX + 1];
        q0[m4*4+0]=a.x; q0[m4*4+1]=a.y; q0[m4*4+2]=a.z; q0[m4*4+3]=a.w;
        q1[m4*4+0]=c.x; q1[m4*4+1]=c.y; q1[m4*4+2]=c.z; q1[m4*4+3]=c.w;
    }
    const float* ksb = ksum + b*CQK;   // uniform
    float dot0 = 0.f, dot1 = 0.f;
    #pragma unroll
    for (int m = 0; m < CQK; ++m) {
        float k = ksb[m];
        dot0 += q0[m] * k; dot1 += q1[m] * k;
    }
    float gm_ = ldx<DT>(gamma, 0);
    float gt0 = gm_ / ((float)NPIX + dot0);
    float gt1 = gm_ / ((float)NPIX + dot1);

    int c0 = cs * 64;
    const float* mb = matT + ((size_t)b*NC + c0)*CQK;  // uniform rows
    const float* vb = vsum + (size_t)b*NC + c0;
    size_t xbase = (size_t)b*NC*NPIX + (size_t)c0*NPIX + p0;

    for (int ci = 0; ci < 64; ci += 8) {
        float xv[8][2];
        #pragma unroll
        for (int u = 0; u < 8; ++u)
            ldx2<DT>(x, xbase + (size_t)(ci+u)*NPIX, xv[u]);
        #pragma unroll
        for (int u = 0; u < 8; ++u) {
            float r0 = vb[ci+u], r1 = r0;
            const float4* mr = (const float4*)(mb + (ci+u)*CQK);  // uniform
            #pragma unroll
            for (int m4 = 0; m4 < 8; ++m4) {
                float4 a = mr[m4];
                r0 += q0[m4*4+0]*a.x + q0[m4*4+1]*a.y + q0[m4*4+2]*a.z + q0[m4*4+3]*a.w;
                r1 += q1[m4*4+0]*a.x + q1[m4*4+1]*a.y + q1[m4*4+2]*a.z + q1[m4*4+3]*a.w;
            }
            float2 o;
            o.x = xv[u][0] + gt0*r0;
            o.y = xv[u][1] + gt1*r1;
            *reinterpret_cast<float2*>(out + xbase + (size_t)(ci+u)*NPIX) = o;
        }
    }
}
__global__ __launch_bounds__(256) void pass2_kernel(
    const void* __restrict__ x, const float4* __restrict__ qn4,
    const float* __restrict__ ksum, const float* __restrict__ matT,
    const float* __restrict__ vsum, const void* __restrict__ gamma,
    float* __restrict__ out, const int* __restrict__ flag) {
    if (flag[0]) pass2_body<1>(x, qn4, ksum, matT, vsum, gamma, out);
    else         pass2_body<0>(x, qn4, ksum, matT, vsum, gamma, out);
}

// ---- host ----------------------------------------------------------------------
extern "C" void kernel_launch(void* const* d_in, const int* in_sizes, int n_in,
                              void* d_out, int out_size, void* d_ws, size_t ws_size,
                              hipStream_t stream)
{
    const void* x  = d_in[0];
    const void* Wq = d_in[1];
    const void* bq = d_in[2];
    const void* Wk = d_in[3];
    const void* bk = d_in[4];
    const void* Wv = d_in[5];
    const void* bv = d_in[6];
    const void* gm = d_in[7];
    float* out = (float*)d_out;

    float* ws = (float*)d_ws;
    int*   flag = (int*)ws;             // 16 floats reserved
    float* wkqT = ws + 16;              // 16384
    float* bkq  = wkqT + 64*NC;         // 64
    float* matT = bkq + 64;             // NB*NC*CQK = 65536
    float* vsum = matT + NB*NC*CQK;     // 2048
    float* ksum = vsum + NB*NC;         // 256
    float* qn4f = ksum + NB*CQK;        // NB*8*NPIX*4 = 4194304 (16B-aligned)
    float* partial_ws = qn4f + (size_t)NB*8*NPIX*4;

    // Partial S scratch: NB*PB*PARTF floats = 34.7 MB (the proven-fit size).
    // Prefer ws; alias into d_out only if ws can't hold it (d_out is fully
    // rewritten by pass2, stream-ordered after pass15 consumes partials).
    size_t fixedf = (size_t)(partial_ws - ws);
    size_t needb  = (fixedf + (size_t)NB*PB*PARTF) * sizeof(float);
    float* partial = (needb <= ws_size) ? partial_ws : (float*)d_out;

    hipLaunchKernelGGL(detprep_kernel, dim3(1), dim3(256), 0, stream,
                       (const bfraw*)x, Wq, bq, Wk, bk, flag, wkqT, bkq);
    hipLaunchKernelGGL(pass1_kernel, dim3(NB*PB), dim3(256), 0, stream,
                       x, wkqT, bkq, (float4*)qn4f, partial, flag);
    hipLaunchKernelGGL(pass15_kernel, dim3(NB*33), dim3(256), 0, stream,
                       partial, Wv, bv, matT, vsum, ksum, flag);
    hipLaunchKernelGGL(pass2_kernel, dim3(NB*32*4), dim3(256), 0, stream,
                       x, (const float4*)qn4f, ksum, matT, vsum, gm, out, flag);
}